// Round 3
// baseline (1010.680 us; speedup 1.0000x reference)
//
#include <hip/hip_runtime.h>
#include <hip/hip_bf16.h>

#define B_    4
#define N_    16384
#define K_    16
#define CIN_  64
#define CF_   67          // 3 + 64 concat channels
#define COUT_ 128
#define AGG_  1072        // 16*67
#define AGGP_ 1088        // padded K for MFMA loop (34*32), zero-filled
#define P_    16          // points per block
#define FSTR  68          // floats per transposed feature record (272 B)
#define ASTR  1096        // aggT row stride in shorts; 548 dwords % 32 == 4
#define NEG_  0.1f

typedef __attribute__((ext_vector_type(8))) short short8;
typedef __attribute__((ext_vector_type(4))) float f32x4;

__device__ __forceinline__ short f2b(float f) {
    __hip_bfloat16 h = __float2bfloat16(f);
    return *reinterpret_cast<short*>(&h);
}
__device__ __forceinline__ float leaky(float x) { return x >= 0.f ? x : NEG_ * x; }

// ---------------------------------------------------------------------------
// Kernel 1: transpose concat(xyz, features) from [B][C][N] fp32 to
// [B][N][FSTR] fp32 so per-neighbor gathers are contiguous 272-byte records.
// ---------------------------------------------------------------------------
__global__ __launch_bounds__(256) void pc_transpose(
    const float* __restrict__ xyz,
    const float* __restrict__ feats,
    float* __restrict__ ft)
{
    __shared__ __align__(16) float st[64][FSTR];   // [j_local][c], 17.4 KB
    const int bid = blockIdx.x;                    // B_ * (N_/64) = 1024
    const int b  = bid >> 8;
    const int j0 = (bid & 255) << 6;
    const int t  = threadIdx.x;
    const int jl = t & 63, cs = t >> 6;            // 4 c-strips

    for (int c = cs; c < FSTR; c += 4) {
        float v = 0.f;
        if (c < 3)        v = xyz  [((size_t)b * 3    + c)       * N_ + j0 + jl];
        else if (c < CF_) v = feats[((size_t)b * CIN_ + (c - 3)) * N_ + j0 + jl];
        st[jl][c] = v;
    }
    __syncthreads();

    f32x4*       dst4 = (f32x4*)(ft + (size_t)(b * N_ + j0) * FSTR);
    const f32x4* st4  = (const f32x4*)&st[0][0];   // 64*17 vec4s, rows contiguous
    for (int i = t; i < 64 * 17; i += 256) dst4[i] = st4[i];
}

// ---------------------------------------------------------------------------
// Kernel 2: convert lin_w fp32 [128][1072] -> bf16 [128][AGGP_] (zero-padded)
// ---------------------------------------------------------------------------
__global__ __launch_bounds__(256) void pc_cvtw(
    const float* __restrict__ lin_w, short* __restrict__ lwb)
{
    const int o = blockIdx.x;                      // 128
    const float* src = lin_w + (size_t)o * AGG_;
    short*       dst = lwb   + (size_t)o * AGGP_;
    for (int c = threadIdx.x; c < AGGP_; c += 256)
        dst[c] = (c < AGG_) ? f2b(src[c]) : (short)0;
}

// ---------------------------------------------------------------------------
// Kernel 3: fused weight-net MLP + agg einsum + final linear (bf16 MFMA,
// fp32 accumulate) per 16-point tile.
// LDS: s_W (16 KB, phases 1-2a) unioned with s_aggT (35 KB, phases 2b-3).
// __launch_bounds__(256,4): 4 blocks/CU (LDS 36.1 KB, VGPR <= 128).
// ---------------------------------------------------------------------------
__global__ __launch_bounds__(256, 4) void pc_main(
    const float* __restrict__ ft,
    const int*   __restrict__ knn,
    const float* __restrict__ w1, const float* __restrict__ b1,
    const float* __restrict__ w2, const float* __restrict__ b2,
    const short* __restrict__ lwb, const float* __restrict__ lin_b,
    float* __restrict__ out)
{
    __shared__ __align__(16) char s_mem[P_ * ASTR * 2];   // 35072 B union
    __shared__ int s_idx[P_ * K_];                        // 1 KB
    float* s_W    = (float*)s_mem;     // [k][p][w] fp32, 16 KB   (phases 1-2a)
    short* s_aggT = (short*)s_mem;     // [p][ASTR] bf16, 35 KB   (phases 2b-3)

    const int t   = threadIdx.x;
    const int bid = blockIdx.x;        // B_ * (N_/P_) = 4096
    const int b   = bid >> 10;
    const int n0  = (bid & 1023) << 4;
    const float* ftb = ft + (size_t)b * N_ * FSTR;

    // ---------------- phase 1: weight-net MLP, one thread per (p,k) --------
    {
        const int p = t >> 4, k = t & 15;
        const int n = n0 + p;
        const int j = knn[((size_t)(b * N_ + n)) * K_ + k];
        s_idx[p * K_ + k] = j;
        const f32x4 rj = *(const f32x4*)(ftb + (size_t)j * FSTR);
        const f32x4 rn = *(const f32x4*)(ftb + (size_t)n * FSTR);
        const float dx0 = rj.x - rn.x;
        const float dx1 = rj.y - rn.y;
        const float dx2 = rj.z - rn.z;
        float h[8];
#pragma unroll
        for (int i = 0; i < 8; i++)
            h[i] = leaky(b1[i] + w1[i*3+0]*dx0 + w1[i*3+1]*dx1 + w1[i*3+2]*dx2);
        float* dst = s_W + (k * 16 + p) * 16;
#pragma unroll
        for (int w = 0; w < 16; w++) {
            float a = b2[w];
#pragma unroll
            for (int i = 0; i < 8; i++) a += w2[w*8+i] * h[i];
            dst[w] = leaky(a);
        }
    }
    __syncthreads();

    // ---------------- phase 2a: agg into registers -------------------------
    // thread (p,s): owns c = 4s..4s+3 (float4) and c = 64+s for s<3.
    const int p = t >> 4, s = t & 15;
    f32x4 acc[16];                     // [w] x 4 c
    float accE[16];                    // [w], tail channel (s<3 only)
#pragma unroll
    for (int w = 0; w < 16; w++) { acc[w] = (f32x4){0.f,0.f,0.f,0.f}; accE[w] = 0.f; }
    {
        const int* idxp = s_idx + p * K_;
        const bool tl = (s < 3);
        for (int k = 0; k < K_; k++) {
            const int j = idxp[k];
            const float* rec = ftb + (size_t)j * FSTR;
            const f32x4 f0 = *(const f32x4*)(rec + 4 * s);
            const float fe = tl ? rec[64 + s] : 0.f;
            const float* Wr = s_W + (k * 16 + p) * 16;   // broadcast across 16 lanes
#pragma unroll
            for (int g = 0; g < 4; g++) {
                const f32x4 w4 = *(const f32x4*)(Wr + 4 * g);
                acc[4*g+0] += f0 * w4.x;  accE[4*g+0] += fe * w4.x;
                acc[4*g+1] += f0 * w4.y;  accE[4*g+1] += fe * w4.y;
                acc[4*g+2] += f0 * w4.z;  accE[4*g+2] += fe * w4.z;
                acc[4*g+3] += f0 * w4.w;  accE[4*g+3] += fe * w4.w;
            }
        }
    }
    __syncthreads();   // all s_W reads done before union region is rewritten

    // ---------------- phase 2b: regs -> s_aggT (bf16) ----------------------
    {
        short* arow = s_aggT + p * ASTR;
#pragma unroll
        for (int w = 0; w < 16; w++) {
            const int c0 = w * CF_ + 4 * s;
            arow[c0 + 0] = f2b(acc[w].x);
            arow[c0 + 1] = f2b(acc[w].y);
            arow[c0 + 2] = f2b(acc[w].z);
            arow[c0 + 3] = f2b(acc[w].w);
            if (s < 3) arow[w * CF_ + 64 + s] = f2b(accE[w]);
        }
        // zero the pad region [1072, 1096) of each row
        for (int z = t; z < P_ * 24; z += 256)
            s_aggT[(z / 24) * ASTR + AGG_ + (z % 24)] = 0;
    }
    __syncthreads();

    // ---------------- phase 3: out[128 x 16] = L[128x1072] @ aggT^T --------
    {
        const int lane = t & 63, wid = t >> 6;
        const int quad = lane >> 4, pr = lane & 15;
        const int kq = quad * 8;
        // A fragment: lane holds A[m=pr][k=quad*8+j]; A row = out channel
        const short* a0p = lwb + (size_t)(wid * 32 + pr) * AGGP_ + kq;
        const short* a1p = a0p + 16 * AGGP_;
        // B fragment: lane holds B[k=quad*8+j][n=pr]; B col = point
        const short* bp  = s_aggT + pr * ASTR + kq;
        f32x4 acc0 = {0.f, 0.f, 0.f, 0.f};
        f32x4 acc1 = {0.f, 0.f, 0.f, 0.f};

#pragma unroll 2
        for (int ks = 0; ks < 34; ks++) {
            const int k = ks * 32;
            const short8 bfr = *(const short8*)(bp + k);
            const short8 a0  = *(const short8*)(a0p + k);
            const short8 a1  = *(const short8*)(a1p + k);
            acc0 = __builtin_amdgcn_mfma_f32_16x16x32_bf16(a0, bfr, acc0, 0, 0, 0);
            acc1 = __builtin_amdgcn_mfma_f32_16x16x32_bf16(a1, bfr, acc1, 0, 0, 0);
        }
        // epilogue: D row = quad*4 + r (out channel within tile), D col = pr
        const int o0 = wid * 32 + quad * 4;
#pragma unroll
        for (int r = 0; r < 4; r++) {
            const int oA = o0 + r;
            const int oB = oA + 16;
            const float vA = leaky(acc0[r] + lin_b[oA]);
            const float vB = leaky(acc1[r] + lin_b[oB]);
            out[((size_t)(b * COUT_ + oA)) * N_ + n0 + pr] = vA;
            out[((size_t)(b * COUT_ + oB)) * N_ + n0 + pr] = vB;
        }
    }
}

extern "C" void kernel_launch(void* const* d_in, const int* in_sizes, int n_in,
                              void* d_out, int out_size, void* d_ws, size_t ws_size,
                              hipStream_t stream)
{
    const float* xyz   = (const float*)d_in[0];
    const float* feats = (const float*)d_in[1];
    const int*   knn   = (const int*)d_in[2];
    const float* w1    = (const float*)d_in[3];
    const float* b1    = (const float*)d_in[4];
    const float* w2    = (const float*)d_in[5];
    const float* b2    = (const float*)d_in[6];
    const float* lin_w = (const float*)d_in[7];
    const float* lin_b = (const float*)d_in[8];
    float* out = (float*)d_out;

    float* ft  = (float*)d_ws;                          // [B][N][FSTR] fp32, 17.8 MB
    short* lwb = (short*)((char*)d_ws + (size_t)B_ * N_ * FSTR * sizeof(float));
                                                        // [128][AGGP_] bf16, 272 KB

    hipLaunchKernelGGL(pc_transpose, dim3(B_ * (N_ / 64)), dim3(256), 0, stream,
                       xyz, feats, ft);
    hipLaunchKernelGGL(pc_cvtw, dim3(COUT_), dim3(256), 0, stream, lin_w, lwb);
    hipLaunchKernelGGL(pc_main, dim3(B_ * (N_ / P_)), dim3(256), 0, stream,
                       ft, knn, w1, b1, w2, b2, lwb, lin_b, out);
}

// Round 4
// 519.135 us; speedup vs baseline: 1.9469x; 1.9469x over previous
//
#include <hip/hip_runtime.h>
#include <hip/hip_bf16.h>

#define B_    4
#define N_    16384
#define K_    16
#define CIN_  64
#define CF_   67          // 3 + 64 concat channels
#define COUT_ 128
#define AGGP_ 1088        // 16*68 padded flattening (c=67 slot zero per w-row)
#define P_    16          // points per block
#define FSTR  72          // bf16 record stride in shorts (144 B)
#define ASTR  1096        // aggT row stride in shorts (1088 + 8 pad)
#define NEG_  0.1f

typedef __attribute__((ext_vector_type(8))) short short8;
typedef __attribute__((ext_vector_type(4))) float f32x4;
typedef __attribute__((ext_vector_type(4))) unsigned short ushort4_t;
typedef __attribute__((ext_vector_type(2))) unsigned int uint2_t;

__device__ __forceinline__ float b2f(unsigned short u) {
    union { float f; unsigned u; } v; v.u = ((unsigned)u) << 16; return v.f;
}
__device__ __forceinline__ unsigned short f2b(float f) {
    __hip_bfloat16 h = __float2bfloat16(f);
    return *reinterpret_cast<unsigned short*>(&h);
}
__device__ __forceinline__ float leaky(float x) { return x >= 0.f ? x : NEG_ * x; }

// ---------------------------------------------------------------------------
// Kernel 1 (fused prep):
//  blocks [0,1024):   transpose concat(xyz,features) -> ft bf16 [B][N][FSTR]
//  blocks [1024,1152): convert lin_w fp32 [128][16*67] -> lwb bf16 [128][16*68]
//                      (c=67 slot of each w-row zeroed; matches aggT layout)
// ---------------------------------------------------------------------------
__global__ __launch_bounds__(256) void pc_prep(
    const float* __restrict__ xyz,
    const float* __restrict__ feats,
    const float* __restrict__ lin_w,
    unsigned short* __restrict__ ft,
    short* __restrict__ lwb)
{
    const int bid = blockIdx.x, t = threadIdx.x;
    if (bid < 1024) {
        __shared__ float st[64][68];           // [j_local][c]
        const int b  = bid >> 8;
        const int j0 = (bid & 255) << 6;
        const int jl = t & 63, cs = t >> 6;
        for (int c = cs; c < 68; c += 4) {
            float v = 0.f;
            if (c < 3)        v = xyz  [((size_t)b * 3    + c)       * N_ + j0 + jl];
            else if (c < CF_) v = feats[((size_t)b * CIN_ + (c - 3)) * N_ + j0 + jl];
            st[jl][c] = v;
        }
        __syncthreads();
        unsigned int* outp = (unsigned int*)(ft + (size_t)(b * N_ + j0) * FSTR);
        for (int idx = t; idx < 64 * 36; idx += 256) {   // 36 uints per record
            const int j2 = idx / 36, cu = idx % 36;
            const int c0 = cu * 2, c1 = c0 + 1;
            const unsigned lo = (c0 < CF_) ? (unsigned)f2b(st[j2][c0]) : 0u;
            const unsigned hi = (c1 < CF_) ? (unsigned)f2b(st[j2][c1]) : 0u;
            outp[idx] = lo | (hi << 16);
        }
    } else {
        const int o = bid - 1024;              // 128 out-channel rows
        const float* src = lin_w + (size_t)o * (16 * CF_);
        short*       dst = lwb   + (size_t)o * AGGP_;
        for (int i = t; i < AGGP_; i += 256) {
            const int w = i / 68, c = i % 68;
            dst[i] = (c < CF_) ? (short)f2b(src[w * CF_ + c]) : (short)0;
        }
    }
}

// ---------------------------------------------------------------------------
// Kernel 2: fused weight-net MLP + agg einsum (two w-passes, 40 acc regs)
// + final 128x1088 linear (bf16 MFMA) per 16-point tile.
// LDS: s_W 8 KB (bf16) + s_aggT 35 KB + idx 1 KB = 44.3 KB -> 3 blocks/CU.
// ---------------------------------------------------------------------------
__global__ __launch_bounds__(256, 3) void pc_main(
    const float*          __restrict__ xyz,
    const unsigned short* __restrict__ ft,
    const int*            __restrict__ knn,
    const float* __restrict__ w1, const float* __restrict__ b1,
    const float* __restrict__ w2, const float* __restrict__ b2,
    const short* __restrict__ lwb, const float* __restrict__ lin_b,
    float* __restrict__ out)
{
    __shared__ __align__(16) unsigned short s_W[K_ * P_ * 16];  // [k][p][w] bf16
    __shared__ __align__(16) short s_aggT[P_ * ASTR];           // [p][1096]
    __shared__ int s_idx[P_ * K_];

    const int t   = threadIdx.x;
    const int bid = blockIdx.x;            // 4096
    const int b   = bid >> 10;
    const int n0  = (bid & 1023) << 4;
    const unsigned short* ftb = ft + (size_t)b * N_ * FSTR;

    // ---------------- phase 1: weight-net MLP, one thread per (p,k) --------
    {
        const int p = t >> 4, k = t & 15;
        const int n = n0 + p;
        const int j = knn[((size_t)(b * N_ + n)) * K_ + k];
        s_idx[p * K_ + k] = j;
        const float* xb = xyz + (size_t)b * 3 * N_;   // fp32-exact MLP input
        const float dx0 = xb[j]          - xb[n];
        const float dx1 = xb[N_ + j]     - xb[N_ + n];
        const float dx2 = xb[2 * N_ + j] - xb[2 * N_ + n];
        float h[8];
#pragma unroll
        for (int i = 0; i < 8; i++)
            h[i] = leaky(b1[i] + w1[i*3+0]*dx0 + w1[i*3+1]*dx1 + w1[i*3+2]*dx2);
        short8 v0, v1;
#pragma unroll
        for (int w = 0; w < 16; w++) {
            float a = b2[w];
#pragma unroll
            for (int i = 0; i < 8; i++) a += w2[w*8+i] * h[i];
            const short bv = (short)f2b(leaky(a));
            if (w < 8) v0[w] = bv; else v1[w - 8] = bv;
        }
        unsigned short* dst = s_W + (k * P_ + p) * 16;   // 32 B aligned
        *(short8*)(dst)     = v0;
        *(short8*)(dst + 8) = v1;
    }
    __syncthreads();

    // ---------------- phase 2: agg[w][c] = sum_k W[k][w]*F[k][c], 2 passes -
    {
        const int p = t >> 4, s = t & 15;
        const int* idxp = s_idx + p * K_;
        short* arow = s_aggT + p * ASTR;
        const bool tl = (s < 3);

#pragma unroll
        for (int hw = 0; hw < 2; hw++) {
            f32x4 acc[8];
            float accE[8];
#pragma unroll
            for (int w = 0; w < 8; w++) { acc[w] = (f32x4){0.f,0.f,0.f,0.f}; accE[w] = 0.f; }

            for (int k = 0; k < K_; k++) {
                const int j = idxp[k];
                const unsigned short* rec = ftb + (size_t)j * FSTR;
                const ushort4_t f4 = *(const ushort4_t*)(rec + 4 * s);
                const float fe = tl ? b2f(rec[64 + s]) : 0.f;
                f32x4 fv;
                fv.x = b2f(f4.x); fv.y = b2f(f4.y);
                fv.z = b2f(f4.z); fv.w = b2f(f4.w);
                const short8 wfr = *(const short8*)(s_W + (k * P_ + p) * 16 + 8 * hw);
#pragma unroll
                for (int w = 0; w < 8; w++) {
                    const float wv = b2f((unsigned short)wfr[w]);
                    acc[w]  += fv * wv;
                    accE[w] += fe * wv;
                }
            }
            // write rows w = 8*hw .. 8*hw+7 (aligned b64 + tail scalar)
#pragma unroll
            for (int w8 = 0; w8 < 8; w8++) {
                const int w = 8 * hw + w8;
                short* dstp = arow + w * 68 + 4 * s;     // 8 B aligned
                uint2_t pk;
                pk.x = (unsigned)f2b(acc[w8].x) | ((unsigned)f2b(acc[w8].y) << 16);
                pk.y = (unsigned)f2b(acc[w8].z) | ((unsigned)f2b(acc[w8].w) << 16);
                *(uint2_t*)dstp = pk;
                if (tl) arow[w * 68 + 64 + s] = (short)f2b(accE[w8]);
            }
        }
        // zero pads: per point: c=67 slot of each w-row (16) + [1088,1096) (8)
        for (int z = t; z < P_ * 24; z += 256) {
            const int pp = z / 24, q = z % 24;
            const int pos = (q < 16) ? (q * 68 + 67) : (AGGP_ + q - 16);
            s_aggT[pp * ASTR + pos] = 0;
        }
    }
    __syncthreads();

    // ---------------- phase 3: out[128 x 16] = L[128x1088] @ aggT^T --------
    {
        const int lane = t & 63, wid = t >> 6;
        const int quad = lane >> 4, pr = lane & 15;
        const int kq = quad * 8;
        // A fragment: lane holds A[m=pr][k=quad*8+j]; A row = out channel
        const short* a0p = lwb + (size_t)(wid * 32 + pr) * AGGP_ + kq;
        const short* a1p = a0p + 16 * AGGP_;
        // B fragment: lane holds B[k=quad*8+j][n=pr]; B col = point
        const short* bp  = s_aggT + pr * ASTR + kq;
        f32x4 acc0 = {0.f, 0.f, 0.f, 0.f};
        f32x4 acc1 = {0.f, 0.f, 0.f, 0.f};

#pragma unroll 2
        for (int ks = 0; ks < 34; ks++) {
            const int k = ks * 32;
            const short8 bfr = *(const short8*)(bp + k);
            const short8 a0  = *(const short8*)(a0p + k);
            const short8 a1  = *(const short8*)(a1p + k);
            acc0 = __builtin_amdgcn_mfma_f32_16x16x32_bf16(a0, bfr, acc0, 0, 0, 0);
            acc1 = __builtin_amdgcn_mfma_f32_16x16x32_bf16(a1, bfr, acc1, 0, 0, 0);
        }
        // epilogue: D row = quad*4 + r (out channel within tile), D col = pr
        const int o0 = wid * 32 + quad * 4;
#pragma unroll
        for (int r = 0; r < 4; r++) {
            const int oA = o0 + r;
            const int oB = oA + 16;
            const float vA = leaky(acc0[r] + lin_b[oA]);
            const float vB = leaky(acc1[r] + lin_b[oB]);
            out[((size_t)(b * COUT_ + oA)) * N_ + n0 + pr] = vA;
            out[((size_t)(b * COUT_ + oB)) * N_ + n0 + pr] = vB;
        }
    }
}

extern "C" void kernel_launch(void* const* d_in, const int* in_sizes, int n_in,
                              void* d_out, int out_size, void* d_ws, size_t ws_size,
                              hipStream_t stream)
{
    const float* xyz   = (const float*)d_in[0];
    const float* feats = (const float*)d_in[1];
    const int*   knn   = (const int*)d_in[2];
    const float* w1    = (const float*)d_in[3];
    const float* b1    = (const float*)d_in[4];
    const float* w2    = (const float*)d_in[5];
    const float* b2    = (const float*)d_in[6];
    const float* lin_w = (const float*)d_in[7];
    const float* lin_b = (const float*)d_in[8];
    float* out = (float*)d_out;

    unsigned short* ft = (unsigned short*)d_ws;              // 9.44 MB bf16
    short* lwb = (short*)((char*)d_ws + (size_t)B_ * N_ * FSTR * sizeof(short));
                                                             // 128*1088*2 = 278 KB

    hipLaunchKernelGGL(pc_prep, dim3(1024 + COUT_), dim3(256), 0, stream,
                       xyz, feats, lin_w, ft, lwb);
    hipLaunchKernelGGL(pc_main, dim3(B_ * (N_ / P_)), dim3(256), 0, stream,
                       xyz, ft, knn, w1, b1, w2, b2, lwb, lin_b, out);
}

// Round 5
// 307.620 us; speedup vs baseline: 3.2855x; 1.6876x over previous
//
#include <hip/hip_runtime.h>
#include <hip/hip_bf16.h>

#define B_    4
#define N_    16384
#define K_    16
#define CIN_  64
#define CF_   67          // 3 + 64 concat channels
#define COUT_ 128
#define AGGP_ 1088        // 16*68 padded flattening (c=67 slot zero per w-row)
#define P_    16          // points per block
#define FSTR  72          // bf16 record stride in shorts (144 B)
#define ASTR  1096        // aggT row stride in shorts (1088 + 8 pad)
#define NEG_  0.1f

typedef __attribute__((ext_vector_type(8))) short short8;
typedef __attribute__((ext_vector_type(4))) float f32x4;
typedef __attribute__((ext_vector_type(4))) unsigned short ushort4_t;
typedef __attribute__((ext_vector_type(2))) unsigned int uint2_t;

__device__ __forceinline__ float b2f(unsigned short u) {
    union { float f; unsigned u; } v; v.u = ((unsigned)u) << 16; return v.f;
}
__device__ __forceinline__ unsigned short f2b(float f) {
    __hip_bfloat16 h = __float2bfloat16(f);
    return *reinterpret_cast<unsigned short*>(&h);
}
__device__ __forceinline__ float leaky(float x) { return x >= 0.f ? x : NEG_ * x; }

// ---------------------------------------------------------------------------
// Kernel 1 (fused prep):
//  blocks [0,1024):   transpose concat(xyz,features) -> ft bf16 [B][N][FSTR]
//  blocks [1024,1152): convert lin_w fp32 [128][16*67] -> lwb bf16 [128][16*68]
//                      (c=67 slot of each w-row zeroed; matches aggT layout)
// ---------------------------------------------------------------------------
__global__ __launch_bounds__(256) void pc_prep(
    const float* __restrict__ xyz,
    const float* __restrict__ feats,
    const float* __restrict__ lin_w,
    unsigned short* __restrict__ ft,
    short* __restrict__ lwb)
{
    const int bid = blockIdx.x, t = threadIdx.x;
    if (bid < 1024) {
        __shared__ float st[64][68];           // [j_local][c]
        const int b  = bid >> 8;
        const int j0 = (bid & 255) << 6;
        const int jl = t & 63, cs = t >> 6;
        for (int c = cs; c < 68; c += 4) {
            float v = 0.f;
            if (c < 3)        v = xyz  [((size_t)b * 3    + c)       * N_ + j0 + jl];
            else if (c < CF_) v = feats[((size_t)b * CIN_ + (c - 3)) * N_ + j0 + jl];
            st[jl][c] = v;
        }
        __syncthreads();
        unsigned int* outp = (unsigned int*)(ft + (size_t)(b * N_ + j0) * FSTR);
        for (int idx = t; idx < 64 * 36; idx += 256) {   // 36 uints per record
            const int j2 = idx / 36, cu = idx % 36;
            const int c0 = cu * 2, c1 = c0 + 1;
            const unsigned lo = (c0 < CF_) ? (unsigned)f2b(st[j2][c0]) : 0u;
            const unsigned hi = (c1 < CF_) ? (unsigned)f2b(st[j2][c1]) : 0u;
            outp[idx] = lo | (hi << 16);
        }
    } else {
        const int o = bid - 1024;              // 128 out-channel rows
        const float* src = lin_w + (size_t)o * (16 * CF_);
        short*       dst = lwb   + (size_t)o * AGGP_;
        for (int i = t; i < AGGP_; i += 256) {
            const int w = i / 68, c = i % 68;
            dst[i] = (c < CF_) ? (short)f2b(src[w * CF_ + c]) : (short)0;
        }
    }
}

// ---------------------------------------------------------------------------
// Kernel 2: fused weight-net MLP + agg einsum (two w-passes, 40 acc regs)
// + final 128x1088 linear (bf16 MFMA) per 16-point tile.
// LDS: s_W 8 KB (bf16) + s_aggT 35 KB + idx 1 KB = 44.3 KB -> 3 blocks/CU.
// __launch_bounds__(256,2): compiler VGPR cap = 256/2 = 128 (>= ~110 working
// set -> NO SPILL; (256,3) capped at 84 and spilled ~400 B/thread, (256,4)
// capped at 64 and spilled massively -- rounds 3/4 evidence).
// ---------------------------------------------------------------------------
__global__ __launch_bounds__(256, 2) void pc_main(
    const float*          __restrict__ xyz,
    const unsigned short* __restrict__ ft,
    const int*            __restrict__ knn,
    const float* __restrict__ w1, const float* __restrict__ b1,
    const float* __restrict__ w2, const float* __restrict__ b2,
    const short* __restrict__ lwb, const float* __restrict__ lin_b,
    float* __restrict__ out)
{
    __shared__ __align__(16) unsigned short s_W[K_ * P_ * 16];  // [k][p][w] bf16
    __shared__ __align__(16) short s_aggT[P_ * ASTR];           // [p][1096]
    __shared__ int s_idx[P_ * K_];

    const int t   = threadIdx.x;
    const int bid = blockIdx.x;            // 4096
    const int b   = bid >> 10;
    const int n0  = (bid & 1023) << 4;
    const unsigned short* ftb = ft + (size_t)b * N_ * FSTR;

    // ---------------- phase 1: weight-net MLP, one thread per (p,k) --------
    {
        const int p = t >> 4, k = t & 15;
        const int n = n0 + p;
        const int j = knn[((size_t)(b * N_ + n)) * K_ + k];
        s_idx[p * K_ + k] = j;
        const float* xb = xyz + (size_t)b * 3 * N_;   // fp32-exact MLP input
        const float dx0 = xb[j]          - xb[n];
        const float dx1 = xb[N_ + j]     - xb[N_ + n];
        const float dx2 = xb[2 * N_ + j] - xb[2 * N_ + n];
        float h[8];
#pragma unroll
        for (int i = 0; i < 8; i++)
            h[i] = leaky(b1[i] + w1[i*3+0]*dx0 + w1[i*3+1]*dx1 + w1[i*3+2]*dx2);
        short8 v0, v1;
#pragma unroll
        for (int w = 0; w < 16; w++) {
            float a = b2[w];
#pragma unroll
            for (int i = 0; i < 8; i++) a += w2[w*8+i] * h[i];
            const short bv = (short)f2b(leaky(a));
            if (w < 8) v0[w] = bv; else v1[w - 8] = bv;
        }
        unsigned short* dst = s_W + (k * P_ + p) * 16;   // 32 B aligned
        *(short8*)(dst)     = v0;
        *(short8*)(dst + 8) = v1;
    }
    __syncthreads();

    // ---------------- phase 2: agg[w][c] = sum_k W[k][w]*F[k][c], 2 passes -
    {
        const int p = t >> 4, s = t & 15;
        const int* idxp = s_idx + p * K_;
        short* arow = s_aggT + p * ASTR;
        const bool tl = (s < 3);

#pragma unroll
        for (int hw = 0; hw < 2; hw++) {
            f32x4 acc[8];
            float accE[8];
#pragma unroll
            for (int w = 0; w < 8; w++) { acc[w] = (f32x4){0.f,0.f,0.f,0.f}; accE[w] = 0.f; }

            for (int k = 0; k < K_; k++) {
                const int j = idxp[k];
                const unsigned short* rec = ftb + (size_t)j * FSTR;
                const ushort4_t f4 = *(const ushort4_t*)(rec + 4 * s);
                const float fe = tl ? b2f(rec[64 + s]) : 0.f;
                f32x4 fv;
                fv.x = b2f(f4.x); fv.y = b2f(f4.y);
                fv.z = b2f(f4.z); fv.w = b2f(f4.w);
                const short8 wfr = *(const short8*)(s_W + (k * P_ + p) * 16 + 8 * hw);
#pragma unroll
                for (int w = 0; w < 8; w++) {
                    const float wv = b2f((unsigned short)wfr[w]);
                    acc[w]  += fv * wv;
                    accE[w] += fe * wv;
                }
            }
            // write rows w = 8*hw .. 8*hw+7 (aligned b64 + tail scalar)
#pragma unroll
            for (int w8 = 0; w8 < 8; w8++) {
                const int w = 8 * hw + w8;
                short* dstp = arow + w * 68 + 4 * s;     // 8 B aligned
                uint2_t pk;
                pk.x = (unsigned)f2b(acc[w8].x) | ((unsigned)f2b(acc[w8].y) << 16);
                pk.y = (unsigned)f2b(acc[w8].z) | ((unsigned)f2b(acc[w8].w) << 16);
                *(uint2_t*)dstp = pk;
                if (tl) arow[w * 68 + 64 + s] = (short)f2b(accE[w8]);
            }
        }
        // zero pads: per point: c=67 slot of each w-row (16) + [1088,1096) (8)
        for (int z = t; z < P_ * 24; z += 256) {
            const int pp = z / 24, q = z % 24;
            const int pos = (q < 16) ? (q * 68 + 67) : (AGGP_ + q - 16);
            s_aggT[pp * ASTR + pos] = 0;
        }
    }
    __syncthreads();

    // ---------------- phase 3: out[128 x 16] = L[128x1088] @ aggT^T --------
    {
        const int lane = t & 63, wid = t >> 6;
        const int quad = lane >> 4, pr = lane & 15;
        const int kq = quad * 8;
        // A fragment: lane holds A[m=pr][k=quad*8+j]; A row = out channel
        const short* a0p = lwb + (size_t)(wid * 32 + pr) * AGGP_ + kq;
        const short* a1p = a0p + 16 * AGGP_;
        // B fragment: lane holds B[k=quad*8+j][n=pr]; B col = point
        const short* bp  = s_aggT + pr * ASTR + kq;
        f32x4 acc0 = {0.f, 0.f, 0.f, 0.f};
        f32x4 acc1 = {0.f, 0.f, 0.f, 0.f};

#pragma unroll 2
        for (int ks = 0; ks < 34; ks++) {
            const int k = ks * 32;
            const short8 bfr = *(const short8*)(bp + k);
            const short8 a0  = *(const short8*)(a0p + k);
            const short8 a1  = *(const short8*)(a1p + k);
            acc0 = __builtin_amdgcn_mfma_f32_16x16x32_bf16(a0, bfr, acc0, 0, 0, 0);
            acc1 = __builtin_amdgcn_mfma_f32_16x16x32_bf16(a1, bfr, acc1, 0, 0, 0);
        }
        // epilogue: D row = quad*4 + r (out channel within tile), D col = pr
        const int o0 = wid * 32 + quad * 4;
#pragma unroll
        for (int r = 0; r < 4; r++) {
            const int oA = o0 + r;
            const int oB = oA + 16;
            const float vA = leaky(acc0[r] + lin_b[oA]);
            const float vB = leaky(acc1[r] + lin_b[oB]);
            out[((size_t)(b * COUT_ + oA)) * N_ + n0 + pr] = vA;
            out[((size_t)(b * COUT_ + oB)) * N_ + n0 + pr] = vB;
        }
    }
}

extern "C" void kernel_launch(void* const* d_in, const int* in_sizes, int n_in,
                              void* d_out, int out_size, void* d_ws, size_t ws_size,
                              hipStream_t stream)
{
    const float* xyz   = (const float*)d_in[0];
    const float* feats = (const float*)d_in[1];
    const int*   knn   = (const int*)d_in[2];
    const float* w1    = (const float*)d_in[3];
    const float* b1    = (const float*)d_in[4];
    const float* w2    = (const float*)d_in[5];
    const float* b2    = (const float*)d_in[6];
    const float* lin_w = (const float*)d_in[7];
    const float* lin_b = (const float*)d_in[8];
    float* out = (float*)d_out;

    unsigned short* ft = (unsigned short*)d_ws;              // 9.44 MB bf16
    short* lwb = (short*)((char*)d_ws + (size_t)B_ * N_ * FSTR * sizeof(short));
                                                             // 128*1088*2 = 278 KB

    hipLaunchKernelGGL(pc_prep, dim3(1024 + COUT_), dim3(256), 0, stream,
                       xyz, feats, lin_w, ft, lwb);
    hipLaunchKernelGGL(pc_main, dim3(B_ * (N_ / P_)), dim3(256), 0, stream,
                       xyz, ft, knn, w1, b1, w2, b2, lwb, lin_b, out);
}

// Round 6
// 270.698 us; speedup vs baseline: 3.7336x; 1.1364x over previous
//
#include <hip/hip_runtime.h>
#include <hip/hip_bf16.h>

#define B_    4
#define N_    16384
#define K_    16
#define CIN_  64
#define CF_   67          // 3 + 64 concat channels
#define COUT_ 128
#define AGGP_ 1088        // 16*68 padded flattening (c=67 slot zero per w-row)
#define P_    16          // points per block
#define FSTR  72          // bf16 record stride in shorts (144 B)
#define ASTR  1096        // aggT row stride in shorts (2192 B, 16B-aligned rows)
#define WOFF  832         // W region offset inside a point's row (shorts):
                          // [832,1088) holds W[k][w] bf16 until pass-B overwrites
#define NEG_  0.1f

typedef __attribute__((ext_vector_type(8))) short short8;
typedef __attribute__((ext_vector_type(4))) float f32x4;
typedef __attribute__((ext_vector_type(4))) unsigned short ushort4_t;
typedef __attribute__((ext_vector_type(2))) unsigned int uint2_t;

__device__ __forceinline__ float b2f(unsigned short u) {
    union { float f; unsigned u; } v; v.u = ((unsigned)u) << 16; return v.f;
}
__device__ __forceinline__ unsigned short f2b(float f) {
    __hip_bfloat16 h = __float2bfloat16(f);
    return *reinterpret_cast<unsigned short*>(&h);
}
__device__ __forceinline__ float leaky(float x) { return x >= 0.f ? x : NEG_ * x; }

// ---------------------------------------------------------------------------
// Kernel 1 (fused prep):
//  blocks [0,1024):   transpose concat(xyz,features) -> ft bf16 [B][N][FSTR]
//  blocks [1024,1152): convert lin_w fp32 [128][16*67] -> lwb bf16 [128][16*68]
// ---------------------------------------------------------------------------
__global__ __launch_bounds__(256) void pc_prep(
    const float* __restrict__ xyz,
    const float* __restrict__ feats,
    const float* __restrict__ lin_w,
    unsigned short* __restrict__ ft,
    short* __restrict__ lwb)
{
    const int bid = blockIdx.x, t = threadIdx.x;
    if (bid < 1024) {
        __shared__ float st[64][68];           // [j_local][c]
        const int b  = bid >> 8;
        const int j0 = (bid & 255) << 6;
        const int jl = t & 63, cs = t >> 6;
        for (int c = cs; c < 68; c += 4) {
            float v = 0.f;
            if (c < 3)        v = xyz  [((size_t)b * 3    + c)       * N_ + j0 + jl];
            else if (c < CF_) v = feats[((size_t)b * CIN_ + (c - 3)) * N_ + j0 + jl];
            st[jl][c] = v;
        }
        __syncthreads();
        unsigned int* outp = (unsigned int*)(ft + (size_t)(b * N_ + j0) * FSTR);
        for (int idx = t; idx < 64 * 36; idx += 256) {   // 36 uints per record
            const int j2 = idx / 36, cu = idx % 36;
            const int c0 = cu * 2, c1 = c0 + 1;
            const unsigned lo = (c0 < CF_) ? (unsigned)f2b(st[j2][c0]) : 0u;
            const unsigned hi = (c1 < CF_) ? (unsigned)f2b(st[j2][c1]) : 0u;
            outp[idx] = lo | (hi << 16);
        }
    } else {
        const int o = bid - 1024;              // 128 out-channel rows
        const float* src = lin_w + (size_t)o * (16 * CF_);
        short*       dst = lwb   + (size_t)o * AGGP_;
        for (int i = t; i < AGGP_; i += 256) {
            const int w = i / 68, c = i % 68;
            dst[i] = (c < CF_) ? (short)f2b(src[w * CF_ + c]) : (short)0;
        }
    }
}

// ---------------------------------------------------------------------------
// Kernel 2: fused weight-net MLP + agg einsum + final linear per 16-pt tile.
// Phases 1-2 are WAVE-LOCAL (each wave owns 4 points; W lives inside its own
// point's aggT row at WOFF and is consumed before pass-B stores overwrite it;
// DS pipe is in-order per wave). Single __syncthreads before the MFMA phase.
// LDS = 16*1096*2 + 1K idx = 36.1 KB -> 4 blocks/CU.
// __launch_bounds__(256,2): VGPR cap 128 (no spill at ~110 working set;
// rounds 3/4 proved caps 64/84 spill catastrophically).
// ---------------------------------------------------------------------------
__global__ __launch_bounds__(256, 2) void pc_main(
    const float*          __restrict__ xyz,
    const unsigned short* __restrict__ ft,
    const int*            __restrict__ knn,
    const float* __restrict__ w1, const float* __restrict__ b1,
    const float* __restrict__ w2, const float* __restrict__ b2,
    const short* __restrict__ lwb, const float* __restrict__ lin_b,
    float* __restrict__ out)
{
    __shared__ __align__(16) short s_agg[P_ * ASTR];   // 35072 B, rows 16B-aligned
    __shared__ int s_idx[P_ * K_];                     // 1 KB

    const int t   = threadIdx.x;
    const int bid = blockIdx.x;            // 4096
    const int b   = bid >> 10;
    const int n0  = (bid & 1023) << 4;
    const unsigned short* ftb = ft + (size_t)b * N_ * FSTR;

    // ---------------- phase 1: weight-net MLP, one thread per (p,k) --------
    // Wave w handles p in [4w,4w+4): writes only its own rows' W regions.
    {
        const int p = t >> 4, k = t & 15;
        const int n = n0 + p;
        const int j = knn[((size_t)(b * N_ + n)) * K_ + k];
        s_idx[p * K_ + k] = j;
        const float* xb = xyz + (size_t)b * 3 * N_;   // fp32-exact MLP input
        const float dx0 = xb[j]          - xb[n];
        const float dx1 = xb[N_ + j]     - xb[N_ + n];
        const float dx2 = xb[2 * N_ + j] - xb[2 * N_ + n];
        float h[8];
#pragma unroll
        for (int i = 0; i < 8; i++)
            h[i] = leaky(b1[i] + w1[i*3+0]*dx0 + w1[i*3+1]*dx1 + w1[i*3+2]*dx2);
        short8 v0, v1;
#pragma unroll
        for (int w = 0; w < 16; w++) {
            float a = b2[w];
#pragma unroll
            for (int i = 0; i < 8; i++) a += w2[w*8+i] * h[i];
            const short bv = (short)f2b(leaky(a));
            if (w < 8) v0[w] = bv; else v1[w - 8] = bv;
        }
        short* wdst = s_agg + p * ASTR + WOFF + k * 16;   // 16B aligned
        *(short8*)(wdst)     = v0;                        // w0..7
        *(short8*)(wdst + 8) = v1;                        // w8..15
    }
    // no barrier: wave-local (DS ops in-order within a wave)

    // ---------------- phase 2: agg[w][c] = sum_k W[k][w]*F[k][c] -----------
    {
        const int p = t >> 4, s = t & 15;
        short* row = s_agg + p * ASTR;
        const unsigned short* wbase = (const unsigned short*)(row + WOFF);
        const bool tl = (s < 3);

        int jk[16];
        {
            const int* ip = s_idx + p * K_;
#pragma unroll
            for (int k = 0; k < K_; k++) jk[k] = ip[k];
        }
        // ---- issue all 16 gather loads up-front; cache in registers ----
        ushort4_t fbuf[16];
        unsigned  feu[8] = {0,0,0,0,0,0,0,0};
#pragma unroll
        for (int k = 0; k < K_; k++) {
            const unsigned short* rec = ftb + (size_t)jk[k] * FSTR;
            fbuf[k] = *(const ushort4_t*)(rec + 4 * s);
            if (tl) feu[k >> 1] |= ((unsigned)rec[64 + s]) << (16 * (k & 1));
        }
        // ---- pass A: w 0..7 (W frag at +0) ----
        {
            f32x4 acc[8]; float accE[8];
#pragma unroll
            for (int w = 0; w < 8; w++) { acc[w] = (f32x4){0.f,0.f,0.f,0.f}; accE[w] = 0.f; }
#pragma unroll
            for (int k = 0; k < K_; k++) {
                const short8 wfr = *(const short8*)(wbase + k * 16);
                f32x4 fv;
                fv.x = b2f(fbuf[k].x); fv.y = b2f(fbuf[k].y);
                fv.z = b2f(fbuf[k].z); fv.w = b2f(fbuf[k].w);
                const float fev = b2f((unsigned short)(feu[k >> 1] >> (16 * (k & 1))));
#pragma unroll
                for (int w = 0; w < 8; w++) {
                    const float wv = b2f((unsigned short)wfr[w]);
                    acc[w]  += fv * wv;
                    accE[w] += fev * wv;
                }
            }
            __asm__ __volatile__("" ::: "memory");
#pragma unroll
            for (int w = 0; w < 8; w++) {          // rows [0,544): below WOFF
                short* dstp = row + w * 68 + 4 * s;
                uint2_t pk;
                pk.x = (unsigned)f2b(acc[w].x) | ((unsigned)f2b(acc[w].y) << 16);
                pk.y = (unsigned)f2b(acc[w].z) | ((unsigned)f2b(acc[w].w) << 16);
                *(uint2_t*)dstp = pk;
                if (tl) row[w * 68 + 64 + s] = (short)f2b(accE[w]);
            }
        }
        // ---- pass B: w 8..15 (W frag at +8); stores overwrite W after reads
        {
            f32x4 acc[8]; float accE[8];
#pragma unroll
            for (int w = 0; w < 8; w++) { acc[w] = (f32x4){0.f,0.f,0.f,0.f}; accE[w] = 0.f; }
#pragma unroll
            for (int k = 0; k < K_; k++) {
                const short8 wfr = *(const short8*)(wbase + k * 16 + 8);
                f32x4 fv;
                fv.x = b2f(fbuf[k].x); fv.y = b2f(fbuf[k].y);
                fv.z = b2f(fbuf[k].z); fv.w = b2f(fbuf[k].w);
                const float fev = b2f((unsigned short)(feu[k >> 1] >> (16 * (k & 1))));
#pragma unroll
                for (int w = 0; w < 8; w++) {
                    const float wv = b2f((unsigned short)wfr[w]);
                    acc[w]  += fv * wv;
                    accE[w] += fev * wv;
                }
            }
            __asm__ __volatile__("" ::: "memory");  // all W reads before stores
#pragma unroll
            for (int w8 = 0; w8 < 8; w8++) {
                const int w = 8 + w8;
                short* dstp = row + w * 68 + 4 * s;
                uint2_t pk;
                pk.x = (unsigned)f2b(acc[w8].x) | ((unsigned)f2b(acc[w8].y) << 16);
                pk.y = (unsigned)f2b(acc[w8].z) | ((unsigned)f2b(acc[w8].w) << 16);
                *(uint2_t*)dstp = pk;
                if (tl) row[w * 68 + 64 + s] = (short)f2b(accE[w8]);
            }
        }
        // ---- zero pads, wave-local: 24 slots per point, 4 points per wave -
        const int lane = t & 63, wv_ = t >> 6;
        for (int z = lane; z < 96; z += 64) {
            const int pp = (wv_ << 2) + z / 24, q = z % 24;
            const int pos = (q < 16) ? (q * 68 + 67) : (AGGP_ + q - 16);
            s_agg[pp * ASTR + pos] = 0;
        }
    }
    __syncthreads();   // single barrier: aggT complete for all 16 points

    // ---------------- phase 3: out[128 x 16] = L[128x1088] @ aggT^T --------
    {
        const int lane = t & 63, wid = t >> 6;
        const int quad = lane >> 4, pr = lane & 15;
        const int kq = quad * 8;
        // A fragment: lane holds A[m=pr][k=quad*8+j]; A row = out channel
        const short* a0p = lwb + (size_t)(wid * 32 + pr) * AGGP_ + kq;
        const short* a1p = a0p + 16 * AGGP_;
        // B fragment: lane holds B[k=quad*8+j][n=pr]; B col = point
        const short* bp  = s_agg + pr * ASTR + kq;
        f32x4 acc0 = {0.f, 0.f, 0.f, 0.f};
        f32x4 acc1 = {0.f, 0.f, 0.f, 0.f};

        short8 a0n = *(const short8*)(a0p);
        short8 a1n = *(const short8*)(a1p);
        for (int ks = 0; ks < 34; ks++) {
            const short8 a0c = a0n, a1c = a1n;
            if (ks < 33) {
                a0n = *(const short8*)(a0p + 32 * (ks + 1));
                a1n = *(const short8*)(a1p + 32 * (ks + 1));
            }
            const short8 bfr = *(const short8*)(bp + 32 * ks);
            acc0 = __builtin_amdgcn_mfma_f32_16x16x32_bf16(a0c, bfr, acc0, 0, 0, 0);
            acc1 = __builtin_amdgcn_mfma_f32_16x16x32_bf16(a1c, bfr, acc1, 0, 0, 0);
        }
        // epilogue: D row = quad*4 + r (out channel within tile), D col = pr
        const int o0 = wid * 32 + quad * 4;
#pragma unroll
        for (int r = 0; r < 4; r++) {
            const int oA = o0 + r;
            const int oB = oA + 16;
            const float vA = leaky(acc0[r] + lin_b[oA]);
            const float vB = leaky(acc1[r] + lin_b[oB]);
            out[((size_t)(b * COUT_ + oA)) * N_ + n0 + pr] = vA;
            out[((size_t)(b * COUT_ + oB)) * N_ + n0 + pr] = vB;
        }
    }
}

extern "C" void kernel_launch(void* const* d_in, const int* in_sizes, int n_in,
                              void* d_out, int out_size, void* d_ws, size_t ws_size,
                              hipStream_t stream)
{
    const float* xyz   = (const float*)d_in[0];
    const float* feats = (const float*)d_in[1];
    const int*   knn   = (const int*)d_in[2];
    const float* w1    = (const float*)d_in[3];
    const float* b1    = (const float*)d_in[4];
    const float* w2    = (const float*)d_in[5];
    const float* b2    = (const float*)d_in[6];
    const float* lin_w = (const float*)d_in[7];
    const float* lin_b = (const float*)d_in[8];
    float* out = (float*)d_out;

    unsigned short* ft = (unsigned short*)d_ws;              // 9.44 MB bf16
    short* lwb = (short*)((char*)d_ws + (size_t)B_ * N_ * FSTR * sizeof(short));
                                                             // 128*1088*2 = 278 KB

    hipLaunchKernelGGL(pc_prep, dim3(1024 + COUT_), dim3(256), 0, stream,
                       xyz, feats, lin_w, ft, lwb);
    hipLaunchKernelGGL(pc_main, dim3(B_ * (N_ / P_)), dim3(256), 0, stream,
                       xyz, ft, knn, w1, b1, w2, b2, lwb, lin_b, out);
}

// Round 7
// 252.809 us; speedup vs baseline: 3.9978x; 1.0708x over previous
//
#include <hip/hip_runtime.h>
#include <hip/hip_bf16.h>

#define B_    4
#define N_    16384
#define K_    16
#define CIN_  64
#define CF_   67          // 3 + 64 concat channels
#define COUT_ 128
#define AGGP_ 1088        // 16*68 padded flattening (c=67 slot zero per w-row)
#define P_    16          // points per block
#define FSTR  72          // bf16 record stride in shorts (144 B)
#define ASTR  1096        // agg/FT row stride in shorts (2192 B, 16B-aligned)
#define WTS   272         // s_WT point stride in shorts: [w][k] 16x16 + 16 pad
#define NEG_  0.1f

typedef __attribute__((ext_vector_type(8))) short short8;
typedef __attribute__((ext_vector_type(4))) float f32x4;
typedef __attribute__((ext_vector_type(2))) unsigned int uint2_t;
typedef __attribute__((ext_vector_type(4))) unsigned int uint4_t;

__device__ __forceinline__ unsigned short f2b(float f) {
    __hip_bfloat16 h = __float2bfloat16(f);
    return *reinterpret_cast<unsigned short*>(&h);
}
__device__ __forceinline__ float leaky(float x) { return x >= 0.f ? x : NEG_ * x; }

// ---------------------------------------------------------------------------
// Kernel 1 (fused prep):
//  blocks [0,1024):   transpose concat(xyz,features) -> ft bf16 [B][N][FSTR]
//  blocks [1024,1152): convert lin_w fp32 [128][16*67] -> lwb bf16 [128][16*68]
// ---------------------------------------------------------------------------
__global__ __launch_bounds__(256) void pc_prep(
    const float* __restrict__ xyz,
    const float* __restrict__ feats,
    const float* __restrict__ lin_w,
    unsigned short* __restrict__ ft,
    short* __restrict__ lwb)
{
    const int bid = blockIdx.x, t = threadIdx.x;
    if (bid < 1024) {
        __shared__ float st[64][68];           // [j_local][c]
        const int b  = bid >> 8;
        const int j0 = (bid & 255) << 6;
        const int jl = t & 63, cs = t >> 6;
        for (int c = cs; c < 68; c += 4) {
            float v = 0.f;
            if (c < 3)        v = xyz  [((size_t)b * 3    + c)       * N_ + j0 + jl];
            else if (c < CF_) v = feats[((size_t)b * CIN_ + (c - 3)) * N_ + j0 + jl];
            st[jl][c] = v;
        }
        __syncthreads();
        unsigned int* outp = (unsigned int*)(ft + (size_t)(b * N_ + j0) * FSTR);
        for (int idx = t; idx < 64 * 36; idx += 256) {   // 36 uints per record
            const int j2 = idx / 36, cu = idx % 36;
            const int c0 = cu * 2, c1 = c0 + 1;
            const unsigned lo = (c0 < CF_) ? (unsigned)f2b(st[j2][c0]) : 0u;
            const unsigned hi = (c1 < CF_) ? (unsigned)f2b(st[j2][c1]) : 0u;
            outp[idx] = lo | (hi << 16);
        }
    } else {
        const int o = bid - 1024;              // 128 out-channel rows
        const float* src = lin_w + (size_t)o * (16 * CF_);
        short*       dst = lwb   + (size_t)o * AGGP_;
        for (int i = t; i < AGGP_; i += 256) {
            const int w = i / 68, c = i % 68;
            dst[i] = (c < CF_) ? (short)f2b(src[w * CF_ + c]) : (short)0;
        }
    }
}

// ---------------------------------------------------------------------------
// Kernel 2: fused weight-net MLP + MFMA agg einsum + MFMA final linear.
// Phases 1-2 wave-local (wave owns 4 points); single barrier before phase 3.
// agg einsum via block-diagonal pair MFMA: one 16x16x32 computes the 8-wide
// c-chunk of TWO points (rows 0-7 = pt A, 8-15 = pt B; K-cols 0-15 = A's k,
// 16-31 = B's k). FT[c][k] lives in the agg row region (union; in-wave DS
// ordering validated in round 6). LDS 44.8 KB -> 3 blocks/CU.
// __launch_bounds__(256,2): VGPR cap 128 (caps 64/84 spilled - rounds 3/4).
// ---------------------------------------------------------------------------
__global__ __launch_bounds__(256, 2) void pc_main(
    const float*          __restrict__ xyz,
    const unsigned short* __restrict__ ft,
    const int*            __restrict__ knn,
    const float* __restrict__ w1, const float* __restrict__ b1,
    const float* __restrict__ w2, const float* __restrict__ b2,
    const short* __restrict__ lwb, const float* __restrict__ lin_b,
    float* __restrict__ out)
{
    __shared__ __align__(16) short s_agg[P_ * ASTR];   // FT[c][k] then agg[w*68+c]
    __shared__ __align__(16) short s_WT[P_ * WTS];     // [p][w*16+k] bf16
    __shared__ int s_idx[P_ * K_];

    const int t   = threadIdx.x;
    const int bid = blockIdx.x;            // 4096
    const int b   = bid >> 10;
    const int n0  = (bid & 1023) << 4;
    const unsigned short* ftb = ft + (size_t)b * N_ * FSTR;

    // ---------------- phase 1: weight-net MLP, one thread per (p,k) --------
    {
        const int p = t >> 4, k = t & 15;
        const int n = n0 + p;
        const int j = knn[((size_t)(b * N_ + n)) * K_ + k];
        s_idx[p * K_ + k] = j;
        const float* xb = xyz + (size_t)b * 3 * N_;   // fp32-exact MLP input
        const float dx0 = xb[j]          - xb[n];
        const float dx1 = xb[N_ + j]     - xb[N_ + n];
        const float dx2 = xb[2 * N_ + j] - xb[2 * N_ + n];
        float h[8];
#pragma unroll
        for (int i = 0; i < 8; i++)
            h[i] = leaky(b1[i] + w1[i*3+0]*dx0 + w1[i*3+1]*dx1 + w1[i*3+2]*dx2);
        short* wd = s_WT + p * WTS + k;               // WT[p][w][k], stride 16
#pragma unroll
        for (int w = 0; w < 16; w++) {
            float a = b2[w];
#pragma unroll
            for (int i = 0; i < 8; i++) a += w2[w*8+i] * h[i];
            wd[w * 16] = (short)f2b(leaky(a));
        }
    }
    __asm__ __volatile__("" ::: "memory");   // wave-local: DS pipe in-order

    // ---------------- phase 2a: gather + register transpose -> FT[c][k] ----
    {
        const int p = t >> 4, s = t & 15;
        const int* ip = s_idx + p * K_;
        const bool tl = (s < 3);
        uint2_t fb[K_];
        unsigned feu[8] = {0,0,0,0,0,0,0,0};
#pragma unroll
        for (int k = 0; k < K_; k++) {
            const unsigned short* rec = ftb + (size_t)ip[k] * FSTR;
            fb[k] = *(const uint2_t*)(rec + 4 * s);
            if (tl) feu[k >> 1] |= ((unsigned)rec[64 + s]) << (16 * (k & 1));
        }
        short* frow = s_agg + p * ASTR;
#pragma unroll
        for (int i = 0; i < 4; i++) {        // rows c = 4s+i, k-contiguous
            const unsigned sel = (i & 1) ? 0x07060302u : 0x05040100u;
            unsigned pk[8];
#pragma unroll
            for (int d = 0; d < 8; d++) {
                const unsigned lo = (i < 2) ? fb[2*d].x   : fb[2*d].y;
                const unsigned hi = (i < 2) ? fb[2*d+1].x : fb[2*d+1].y;
                pk[d] = __builtin_amdgcn_perm(hi, lo, sel);
            }
            const int c = 4 * s + i;
            uint4_t q0 = { pk[0], pk[1], pk[2], pk[3] };
            uint4_t q1 = { pk[4], pk[5], pk[6], pk[7] };
            *(uint4_t*)(frow + c * 16)     = q0;
            *(uint4_t*)(frow + c * 16 + 8) = q1;
        }
        if (tl) {                            // tail rows c = 64..66
            uint4_t q0 = { feu[0], feu[1], feu[2], feu[3] };
            uint4_t q1 = { feu[4], feu[5], feu[6], feu[7] };
            *(uint4_t*)(frow + (64 + s) * 16)     = q0;
            *(uint4_t*)(frow + (64 + s) * 16 + 8) = q1;
        }
        if (s == 3) {                        // row 67 = zero (agg[w][67]=0)
            uint4_t z = {0u, 0u, 0u, 0u};
            *(uint4_t*)(frow + 67 * 16)     = z;
            *(uint4_t*)(frow + 67 * 16 + 8) = z;
        }
    }
    __asm__ __volatile__("" ::: "memory");

    // ---------------- phase 2b: pair MFMA agg, overwrite FT with agg -------
    {
        const int lane = t & 63;
        const int wq   = lane >> 4;          // quad
        const int pr   = lane & 15;
        const int pb   = (t >> 6) * 4;       // wave's first point
        const int kh   = (wq & 1) * 8;       // k-halfword within a point
        const int side = (wq < 2) ? 0 : 1;   // B-operand / D-row point select
        const int asid = (pr < 8) ? 0 : 1;   // A-operand point select
        const bool act = (side == asid);
        const int cq   = 4 * (wq & 1);
#pragma unroll
        for (int pair = 0; pair < 2; pair++) {
            const int pA = pb + 2 * pair;
            const short8 bfr = *(const short8*)(s_WT + (pA + side) * WTS + pr * 16 + kh);
            const short* ap  = s_agg + (size_t)(pA + asid) * ASTR + (pr & 7) * 16 + kh;
            f32x4 D[9];
#pragma unroll
            for (int cc = 0; cc < 9; cc++) {
                short8 af = {0,0,0,0,0,0,0,0};
                // cc=8 reads rows 64..67 only (rows 68+ would run past the row)
                if (act && (cc < 8 || (pr & 7) < 4))
                    af = *(const short8*)(ap + 128 * cc);
                D[cc] = __builtin_amdgcn_mfma_f32_16x16x32_bf16(
                            af, bfr, (f32x4){0.f,0.f,0.f,0.f}, 0, 0, 0);
            }
            __asm__ __volatile__("" ::: "memory");  // all FT reads before stores
            short* arow = s_agg + (size_t)(pA + side) * ASTR + pr * 68;  // w=pr
#pragma unroll
            for (int cc = 0; cc < 9; cc++) {
                if (cc == 8 && cq != 0) continue;   // c=68..71 skipped
                const unsigned lo = (unsigned)f2b(D[cc].x) | ((unsigned)f2b(D[cc].y) << 16);
                const unsigned hi = (unsigned)f2b(D[cc].z) | ((unsigned)f2b(D[cc].w) << 16);
                uint2_t pk2 = { lo, hi };
                *(uint2_t*)(arow + 8 * cc + cq) = pk2;
            }
        }
    }
    __syncthreads();   // agg complete for all 16 points

    // ---------------- phase 3: out[128 x 16] = L[128x1088] @ aggT^T --------
    {
        const int lane = t & 63, wid = t >> 6;
        const int quad = lane >> 4, pr = lane & 15;
        const int kq = quad * 8;
        // A fragment: lane holds A[m=pr][k=quad*8+j]; A row = out channel
        const short* a0p = lwb + (size_t)(wid * 32 + pr) * AGGP_ + kq;
        const short* a1p = a0p + 16 * AGGP_;
        // B fragment: lane holds B[k=quad*8+j][n=pr]; B col = point
        const short* bp  = s_agg + pr * ASTR + kq;
        f32x4 acc0 = {0.f, 0.f, 0.f, 0.f};
        f32x4 acc1 = {0.f, 0.f, 0.f, 0.f};

        short8 a0n = *(const short8*)(a0p);
        short8 a1n = *(const short8*)(a1p);
        for (int ks = 0; ks < 34; ks++) {
            const short8 a0c = a0n, a1c = a1n;
            if (ks < 33) {
                a0n = *(const short8*)(a0p + 32 * (ks + 1));
                a1n = *(const short8*)(a1p + 32 * (ks + 1));
            }
            const short8 bfr = *(const short8*)(bp + 32 * ks);
            acc0 = __builtin_amdgcn_mfma_f32_16x16x32_bf16(a0c, bfr, acc0, 0, 0, 0);
            acc1 = __builtin_amdgcn_mfma_f32_16x16x32_bf16(a1c, bfr, acc1, 0, 0, 0);
        }
        // epilogue: D row = quad*4 + r (out channel within tile), D col = pr
        const int o0 = wid * 32 + quad * 4;
#pragma unroll
        for (int r = 0; r < 4; r++) {
            const int oA = o0 + r;
            const int oB = oA + 16;
            const float vA = leaky(acc0[r] + lin_b[oA]);
            const float vB = leaky(acc1[r] + lin_b[oB]);
            out[((size_t)(b * COUT_ + oA)) * N_ + n0 + pr] = vA;
            out[((size_t)(b * COUT_ + oB)) * N_ + n0 + pr] = vB;
        }
    }
}

extern "C" void kernel_launch(void* const* d_in, const int* in_sizes, int n_in,
                              void* d_out, int out_size, void* d_ws, size_t ws_size,
                              hipStream_t stream)
{
    const float* xyz   = (const float*)d_in[0];
    const float* feats = (const float*)d_in[1];
    const int*   knn   = (const int*)d_in[2];
    const float* w1    = (const float*)d_in[3];
    const float* b1    = (const float*)d_in[4];
    const float* w2    = (const float*)d_in[5];
    const float* b2    = (const float*)d_in[6];
    const float* lin_w = (const float*)d_in[7];
    const float* lin_b = (const float*)d_in[8];
    float* out = (float*)d_out;

    unsigned short* ft = (unsigned short*)d_ws;              // 9.44 MB bf16
    short* lwb = (short*)((char*)d_ws + (size_t)B_ * N_ * FSTR * sizeof(short));
                                                             // 128*1088*2 = 278 KB

    hipLaunchKernelGGL(pc_prep, dim3(1024 + COUT_), dim3(256), 0, stream,
                       xyz, feats, lin_w, ft, lwb);
    hipLaunchKernelGGL(pc_main, dim3(B_ * (N_ / P_)), dim3(256), 0, stream,
                       xyz, ft, knn, w1, b1, w2, b2, lwb, lin_b, out);
}